// Round 20
// baseline (1491.964 us; speedup 1.0000x reference)
//
#include <hip/hip_runtime.h>
#include <math.h>

#define N_NODES 50000
#define N_EDGES 100000
#define H 768
#define NH 12
#define HD 64
#define NG 64
#define NC 10
#define H2 384
#define PCH 32   // pooling chunks per graph
#define NSB 196  // scan blocks = cdiv(N_NODES,256)

typedef _Float16 h8  __attribute__((ext_vector_type(8)));   // 8 fp16 (4 VGPR)
typedef _Float16 h4v __attribute__((ext_vector_type(4)));
typedef float    ffrag __attribute__((ext_vector_type(4))); // MFMA acc

// ---------------- static device scratch ----------------
__device__ _Float16 g_ah[(size_t)N_NODES * H];     // GEMM input acts fp16
__device__ _Float16 g_ch[(size_t)N_NODES * H];     // GEMM output / gather input fp16
__device__ _Float16 g_wh[4 * H * H];               // 4 weights^T fp16 [N][K]
__device__ float    g_dinv[N_NODES];
__device__ int      g_degi[N_NODES];
__device__ int      g_bsum[256];
__device__ int      g_boff[256];
__device__ int      g_cursor[N_NODES];
__device__ int      g_rowptr[N_NODES + 1];
__device__ int      g_csrsrc[N_EDGES];
__device__ float    g_aS[(size_t)N_NODES * NH];
__device__ float    g_aD[(size_t)N_NODES * NH];
__device__ float    g_selfc[(size_t)N_NODES * NH]; // GAT self-coefficient
__device__ float    g_coef[(size_t)N_EDGES * NH];  // GAT per-edge coefficient (4.8 MB)
__device__ float    g_ppool[(size_t)NG * PCH * H]; // pooling partials (6.3 MB)

__device__ inline int clampi(int v, int hi) { return (v < 0) ? 0 : (v >= hi ? hi - 1 : v); }

// async global->LDS, 16B per lane: lane i writes lds_base + i*16 (wave-uniform base)
__device__ inline void gload_lds16(const _Float16* g, _Float16* s) {
    __builtin_amdgcn_global_load_lds(
        (const __attribute__((address_space(1))) void*)g,
        (__attribute__((address_space(3))) void*)s, 16, 0, 0);
}

// ---------------- CSR build ----------------
__global__ void fill_i32(int* p, int n, int v) {
    int i = blockIdx.x * blockDim.x + threadIdx.x;
    if (i < n) p[i] = v;
}

__global__ void count_deg(const int* __restrict__ dst, int* __restrict__ degi) {
    int e = blockIdx.x * blockDim.x + threadIdx.x;
    if (e < N_EDGES) atomicAdd(&degi[clampi(dst[e], N_NODES)], 1);
}

// hierarchical scan (r13-verified)
__global__ __launch_bounds__(256) void scan1(const int* __restrict__ degi, int* __restrict__ bsum) {
    __shared__ int s[256];
    int b = blockIdx.x, t = threadIdx.x;
    int idx = b * 256 + t;
    s[t] = (idx < N_NODES) ? degi[idx] : 0;
    __syncthreads();
    for (int off = 128; off > 0; off >>= 1) {
        if (t < off) s[t] += s[t + off];
        __syncthreads();
    }
    if (t == 0) bsum[b] = s[0];
}

__global__ __launch_bounds__(256) void scan2(const int* __restrict__ bsum, int* __restrict__ boff,
                                             int* __restrict__ rowptr) {
    __shared__ int s[256];
    int t = threadIdx.x;
    int v = (t < NSB) ? bsum[t] : 0;
    s[t] = v;
    __syncthreads();
    for (int off = 1; off < 256; off <<= 1) {
        int x = (t >= off) ? s[t - off] : 0;
        __syncthreads();
        s[t] += x;
        __syncthreads();
    }
    if (t < NSB) boff[t] = s[t] - v;
    if (t == NSB - 1) rowptr[N_NODES] = s[t];
}

__global__ __launch_bounds__(256) void scan3(const int* __restrict__ degi, const int* __restrict__ boff,
                                             int* __restrict__ rowptr, int* __restrict__ cursor,
                                             float* __restrict__ dinv) {
    __shared__ int s[256];
    int b = blockIdx.x, t = threadIdx.x;
    int idx = b * 256 + t;
    int v = (idx < N_NODES) ? degi[idx] : 0;
    s[t] = v;
    __syncthreads();
    for (int off = 1; off < 256; off <<= 1) {
        int x = (t >= off) ? s[t - off] : 0;
        __syncthreads();
        s[t] += x;
        __syncthreads();
    }
    if (idx < N_NODES) {
        int excl = s[t] - v + boff[b];
        rowptr[idx] = excl;
        cursor[idx] = excl;
        dinv[idx] = rsqrtf((float)v + 1.0f);   // +1 = self-loop
    }
}

__global__ void bin_edges(const int* __restrict__ src, const int* __restrict__ dst,
                          int* __restrict__ cursor, int* __restrict__ csrsrc) {
    int e = blockIdx.x * blockDim.x + threadIdx.x;
    if (e >= N_EDGES) return;
    int d = clampi(dst[e], N_NODES);
    int pos = atomicAdd(&cursor[d], 1);
    if (pos >= 0 && pos < N_EDGES) csrsrc[pos] = clampi(src[e], N_NODES);
}

// all 4 big weights: w[K][N] fp32 -> transposed fp16 [N][K], one launch
__global__ void split_wT4(const float* __restrict__ w2, const float* __restrict__ w3,
                          const float* __restrict__ wg1, const float* __restrict__ wg2,
                          _Float16* __restrict__ out) {
    int idx = blockIdx.x * blockDim.x + threadIdx.x;
    if (idx >= 4 * H * H) return;
    int l = idx / (H * H), r = idx % (H * H);
    const float* w = (l == 0) ? w2 : (l == 1) ? w3 : (l == 2) ? wg1 : wg2;
    int n = r % H, k = r / H;
    out[(size_t)l * H * H + (size_t)n * H + k] = (_Float16)w[(size_t)k * H + n];
}

// ---- fused GCN1: aggregate x (3-dim!) then matvec w1 + bias + relu + fp16 ----
__global__ void gcn1_fused(const int* __restrict__ rowptr, const int* __restrict__ csrsrc,
                           const float* __restrict__ x, const float* __restrict__ dinv,
                           const float* __restrict__ w1, const float* __restrict__ b1,
                           _Float16* __restrict__ hi) {
    int d = blockIdx.x * 2 + (threadIdx.x / 96);
    int t = threadIdx.x % 96;
    if (d >= N_NODES) return;
    float dd = dinv[d];
    float c = dd * dd;
    float s0 = x[d*3] * c, s1 = x[d*3+1] * c, s2 = x[d*3+2] * c;
    int beg = rowptr[d], end = rowptr[d + 1];
    for (int i = beg; i < end; i++) {
        int s = csrsrc[i];
        float cc = dinv[s] * dd;
        s0 += x[s*3] * cc; s1 += x[s*3+1] * cc; s2 += x[s*3+2] * cc;
    }
    int j0 = t * 8;
    h8 o;
    #pragma unroll
    for (int k = 0; k < 8; k++) {
        int j = j0 + k;
        float v = s0 * w1[j] + s1 * w1[H + j] + s2 * w1[2*H + j] + b1[j];
        o[k] = (_Float16)fmaxf(v, 0.f);
    }
    ((h8*)(hi + (size_t)d * H))[t] = o;
}

// -- fp16 MFMA GEMM: A via LDS (BK=64 dbuf, 32 KB), B direct from L2 ---------
// r19: BK=64 confirmed the barrier-drain model (127->108 us). This round: B
// bypasses LDS. r8's B-bypass failed because the A-prefetch was issued BEFORE
// the B register-loads -> waiting for B forced vmcnt(0), draining the prefetch
// (vmcnt completes in issue order). Fix: issue ALL B loads first, then the A
// prefetch; the compiler's precise wait for B is then vmcnt(2) and A stays in
// flight through the whole MFMA section. B slice (1.2 MB) is L2-resident per
// XCD (r6 swizzle). LDS = A-only dbuf 32 KB -> ~4-5 blocks/CU (VGPR-capped
// ~20 waves/CU vs r19's 11.6).
__global__ __launch_bounds__(512) void gemm_f16(const _Float16* __restrict__ a,
                                                const _Float16* __restrict__ bt,
                                                _Float16* __restrict__ C, int M,
                                                const float* __restrict__ asf,
                                                const float* __restrict__ adf,
                                                float* __restrict__ aS,
                                                float* __restrict__ aD) {
    __shared__ _Float16 sA[2][2][128 * 32];   // [buf][khalf][128 rows x 32 k]
    int tid = threadIdx.x;
    int wave = tid >> 6, lane = tid & 63;
    int quad = lane >> 4, l16 = lane & 15;

    int id = blockIdx.x;
    int x = id & 7;
    int s = id >> 3;
    int strip = x + 8 * (s / 6);
    int colt = s % 6;
    if (strip >= (N_NODES + 127) / 128) return;
    int row0 = strip * 128, col0 = colt * 128;
    int wr = (wave >> 1) * 32, wc = (wave & 1) * 64;   // 4 row-waves x 2 col-waves

    // A staging: 16 segs = khalf(2) x rowgroup(8); wave w stages segs 2w, 2w+1
    int rr = lane >> 2;
    int kc = (((lane & 3) ^ ((lane >> 3) & 3)) << 3);   // XOR-swizzled source chunk
    const _Float16* gptr[2];
    int soff[2];     // khalf*4096 + rowgroup*512
    #pragma unroll
    for (int k = 0; k < 2; k++) {
        int sg = wave * 2 + k;              // 0..15
        int khalf = sg >> 3, rowgroup = sg & 7;
        int r = row0 + rowgroup * 16 + rr;
        if (r >= M) r = M - 1;              // clamped rows feed unstored C rows
        gptr[k] = a + (size_t)r * H + khalf * 32 + kc;
        soff[k] = khalf * 4096 + rowgroup * 512;
    }

    // B fragment base offsets (per lane), column-major [N][K]
    size_t boff[4];
    #pragma unroll
    for (int j = 0; j < 4; j++)
        boff[j] = (size_t)(col0 + wc + j * 16 + l16) * H + quad * 8;

    int fsw = (quad ^ ((l16 >> 1) & 3)) * 8;

    ffrag acc[2][4];
    #pragma unroll
    for (int i = 0; i < 2; i++)
        #pragma unroll
        for (int j = 0; j < 4; j++) { ffrag z = {0.f, 0.f, 0.f, 0.f}; acc[i][j] = z; }

    // prologue: stage A k-tile 0 into buf 0
    #pragma unroll
    for (int k = 0; k < 2; k++)
        gload_lds16(gptr[k], &sA[0][0][0] + soff[k]);

    #pragma unroll 1
    for (int kt = 0; kt < H / 64; kt++) {
        int cur = kt & 1;
        __syncthreads();   // A buf[cur] ready; prior prefetch had a full compute phase

        // 1) B loads FIRST (both khalves) -- must precede the A prefetch so the
        //    compiler's wait for B leaves the prefetch outstanding (vmcnt order)
        h8 fb0[4], fb1[4];
        #pragma unroll
        for (int j = 0; j < 4; j++)
            fb0[j] = *reinterpret_cast<const h8*>(bt + boff[j] + kt * 64);
        #pragma unroll
        for (int j = 0; j < 4; j++)
            fb1[j] = *reinterpret_cast<const h8*>(bt + boff[j] + kt * 64 + 32);

        // 2) A prefetch for kt+1 into the other buffer (stays in flight)
        if (kt + 1 < H / 64) {
            int koff = (kt + 1) * 64;
            #pragma unroll
            for (int k = 0; k < 2; k++)
                gload_lds16(gptr[k] + koff, &sA[cur ^ 1][0][0] + soff[k]);
        }

        // 3) compute: A from LDS, B from the registers loaded above
        #pragma unroll
        for (int kk = 0; kk < 2; kk++) {
            const _Float16* pA = sA[cur][kk];
            h8 fa[2];
            #pragma unroll
            for (int i = 0; i < 2; i++)
                fa[i] = *reinterpret_cast<const h8*>(&pA[(wr + i * 16 + l16) * 32 + fsw]);
            #pragma unroll
            for (int i = 0; i < 2; i++)
                #pragma unroll
                for (int j = 0; j < 4; j++)
                    acc[i][j] = __builtin_amdgcn_mfma_f32_16x16x32_f16(
                        fa[i], (kk ? fb1[j] : fb0[j]), acc[i][j], 0, 0, 0);
        }
    }

    // epilogue: C/D layout col=lane&15, row=quad*4+reg (m89-verified); fp16 store
    #pragma unroll
    for (int i = 0; i < 2; i++)
        #pragma unroll
        for (int r = 0; r < 4; r++) {
            int row = row0 + wr + i * 16 + quad * 4 + r;
            if (row >= M) continue;
            #pragma unroll
            for (int j = 0; j < 4; j++)
                C[(size_t)row * H + col0 + wc + j * 16 + l16] = (_Float16)acc[i][j][r];
        }

    // fused GAT alpha: this wave covers one full head (64 cols) for 32 rows
    if (asf) {
        int head = (col0 + wc) >> 6;
        float as_c[4], ad_c[4];
        #pragma unroll
        for (int j = 0; j < 4; j++) {
            int col = col0 + wc + j * 16 + l16;
            as_c[j] = asf[col];
            ad_c[j] = adf[col];
        }
        #pragma unroll
        for (int i = 0; i < 2; i++)
            #pragma unroll
            for (int r = 0; r < 4; r++) {
                float ps = 0.f, pd = 0.f;
                #pragma unroll
                for (int j = 0; j < 4; j++) {
                    ps += acc[i][j][r] * as_c[j];
                    pd += acc[i][j][r] * ad_c[j];
                }
                ps += __shfl_xor(ps, 1);  pd += __shfl_xor(pd, 1);
                ps += __shfl_xor(ps, 2);  pd += __shfl_xor(pd, 2);
                ps += __shfl_xor(ps, 4);  pd += __shfl_xor(pd, 4);
                ps += __shfl_xor(ps, 8);  pd += __shfl_xor(pd, 8);
                int row = row0 + wr + i * 16 + quad * 4 + r;
                if (l16 == 0 && row < M) {
                    aS[row * NH + head] = ps;
                    aD[row * NH + head] = pd;
                }
            }
    }
}

// ------- fused GCN gather: 2 nodes/block, 16B h8 loads (r14-verified) --------
__global__ void gcn_gather(const int* __restrict__ rowptr, const int* __restrict__ csrsrc,
                           const _Float16* __restrict__ h, const float* __restrict__ dinv,
                           const float* __restrict__ bias, _Float16* __restrict__ hi) {
    int d = blockIdx.x * 2 + (threadIdx.x / 96);
    int t = threadIdx.x % 96;   // h8-chunk index (96 x 8 halves = 768)
    if (d >= N_NODES) return;
    float dd = dinv[d];
    float c = dd * dd;
    h8 v = ((const h8*)(h + (size_t)d * H))[t];
    float acc[8];
    #pragma unroll
    for (int k = 0; k < 8; k++) acc[k] = (float)v[k] * c;
    int beg = rowptr[d], end = rowptr[d + 1];
    for (int i = beg; i < end; i++) {
        int s = csrsrc[i];
        float cc = dinv[s] * dd;
        h8 u = ((const h8*)(h + (size_t)s * H))[t];
        #pragma unroll
        for (int k = 0; k < 8; k++) acc[k] += (float)u[k] * cc;
    }
    float4 b0 = ((const float4*)bias)[2 * t];
    float4 b1 = ((const float4*)bias)[2 * t + 1];
    h8 o;
    o[0] = (_Float16)fmaxf(acc[0] + b0.x, 0.f);
    o[1] = (_Float16)fmaxf(acc[1] + b0.y, 0.f);
    o[2] = (_Float16)fmaxf(acc[2] + b0.z, 0.f);
    o[3] = (_Float16)fmaxf(acc[3] + b0.w, 0.f);
    o[4] = (_Float16)fmaxf(acc[4] + b1.x, 0.f);
    o[5] = (_Float16)fmaxf(acc[5] + b1.y, 0.f);
    o[6] = (_Float16)fmaxf(acc[6] + b1.z, 0.f);
    o[7] = (_Float16)fmaxf(acc[7] + b1.w, 0.f);
    ((h8*)(hi + (size_t)d * H))[t] = o;
}

__device__ inline float lrelu(float v) { return (v > 0.f) ? v : 0.2f * v; }

// ---- GAT softmax stats: one thread per (node, head) (r18-verified) ----
__global__ void gat_stats(const int* __restrict__ rowptr, const int* __restrict__ csrsrc,
                          const float* __restrict__ aS, const float* __restrict__ aD,
                          float* __restrict__ selfc, float* __restrict__ coef) {
    int idx = blockIdx.x * blockDim.x + threadIdx.x;
    if (idx >= N_NODES * NH) return;
    int d = idx / NH, hh = idx % NH;
    int beg = rowptr[d], end = rowptr[d + 1];
    float adv = aD[idx];
    float eself = lrelu(aS[idx] + adv);
    float m = eself;
    for (int i = beg; i < end; i++)
        m = fmaxf(m, lrelu(aS[csrsrc[i] * NH + hh] + adv));
    float ssum = __expf(eself - m);
    for (int i = beg; i < end; i++)
        ssum += __expf(lrelu(aS[csrsrc[i] * NH + hh] + adv) - m);
    float inv = 1.0f / ssum;
    selfc[idx] = __expf(eself - m) * inv;
    for (int i = beg; i < end; i++)
        coef[(size_t)i * NH + hh] = __expf(lrelu(aS[csrsrc[i] * NH + hh] + adv) - m) * inv;
}

// fused GAT aggregation: single pass, precomputed coefficients; fp16 out.
__global__ void gat_gather(const int* __restrict__ rowptr, const int* __restrict__ csrsrc,
                           const _Float16* __restrict__ h, const float* __restrict__ selfc,
                           const float* __restrict__ coef, const float* __restrict__ bias,
                           _Float16* __restrict__ hi, int relu) {
    int d = blockIdx.x * 2 + (threadIdx.x / 96);
    int t = threadIdx.x % 96;
    if (d >= N_NODES) return;
    int hh = t >> 3;
    int beg = rowptr[d], end = rowptr[d + 1];
    float cself = selfc[d * NH + hh];
    h8 v = ((const h8*)(h + (size_t)d * H))[t];
    float acc[8];
    #pragma unroll
    for (int k = 0; k < 8; k++) acc[k] = (float)v[k] * cself;
    for (int i = beg; i < end; i++) {
        int s = csrsrc[i];
        float c = coef[(size_t)i * NH + hh];
        h8 u = ((const h8*)(h + (size_t)s * H))[t];
        #pragma unroll
        for (int k = 0; k < 8; k++) acc[k] += (float)u[k] * c;
    }
    float4 b0 = ((const float4*)bias)[2 * t];
    float4 b1 = ((const float4*)bias)[2 * t + 1];
    acc[0] += b0.x; acc[1] += b0.y; acc[2] += b0.z; acc[3] += b0.w;
    acc[4] += b1.x; acc[5] += b1.y; acc[6] += b1.z; acc[7] += b1.w;
    if (relu) {
        #pragma unroll
        for (int k = 0; k < 8; k++) acc[k] = fmaxf(acc[k], 0.f);
    }
    h8 o;
    #pragma unroll
    for (int k = 0; k < 8; k++) o[k] = (_Float16)acc[k];
    ((h8*)(hi + (size_t)d * H))[t] = o;
}

// ---------------- pooling (batch is sorted), two-stage + fused mlp1+mlp2 ------
__device__ inline int lower_bound_i(const int* b, int n, int key) {
    int lo = 0, hi = n;
    while (lo < hi) { int mid = (lo + hi) >> 1; if (b[mid] < key) lo = mid + 1; else hi = mid; }
    return lo;
}

__global__ void pool_partial(const int* __restrict__ batch, const _Float16* __restrict__ h,
                             float* __restrict__ ppool) {
    int g = blockIdx.x / PCH, c = blockIdx.x % PCH;
    int t = threadIdx.x;   // 0..191, h4v chunks
    int lo = lower_bound_i(batch, N_NODES, g);
    int hi = lower_bound_i(batch, N_NODES, g + 1);
    int len = hi - lo;
    int chunk = (len + PCH - 1) / PCH;
    int s = lo + c * chunk;
    int e = s + chunk; if (e > hi) e = hi;
    float4 a = {0, 0, 0, 0};
    for (int n = s; n < e; n++) {
        h4v v = ((const h4v*)(h + (size_t)n * H))[t];
        a.x += (float)v[0]; a.y += (float)v[1]; a.z += (float)v[2]; a.w += (float)v[3];
    }
    ((float4*)(ppool + (size_t)blockIdx.x * H))[t] = a;
}

// reduce partials -> mean row -> z = relu(row@wc1+bc1) -> logits = z@wc2+bc2
__global__ __launch_bounds__(384) void pool_mlp(const int* __restrict__ batch,
                                                const float* __restrict__ ppool,
                                                const float* __restrict__ wc1,
                                                const float* __restrict__ bc1,
                                                const float* __restrict__ wc2,
                                                const float* __restrict__ bc2,
                                                float* __restrict__ out) {
    __shared__ float row[H];
    __shared__ float z[H2];
    int g = blockIdx.x, t = threadIdx.x;   // 384 threads
    int lo = lower_bound_i(batch, N_NODES, g);
    int hi = lower_bound_i(batch, N_NODES, g + 1);
    float inv = 1.0f / fmaxf((float)(hi - lo), 1.0f);
    for (int c0 = t; c0 < H; c0 += 384) {
        float a = 0.f;
        for (int c = 0; c < PCH; c++) a += ppool[(size_t)(g * PCH + c) * H + c0];
        row[c0] = a * inv;
    }
    __syncthreads();
    float acc = bc1[t];
    for (int k = 0; k < H; k++) acc += row[k] * wc1[(size_t)k * H2 + t];
    z[t] = fmaxf(acc, 0.f);
    __syncthreads();
    if (t < NC) {
        float l = bc2[t];
        for (int k = 0; k < H2; k++) l += z[k] * wc2[(size_t)k * NC + t];
        out[g * NC + t] = l;
    }
}

// ---------------- launch ----------------
extern "C" void kernel_launch(void* const* d_in, const int* in_sizes, int n_in,
                              void* d_out, int out_size, void* d_ws, size_t ws_size,
                              hipStream_t stream) {
    (void)d_ws; (void)ws_size;
    const float* x     = (const float*)d_in[0];
    const int*   ei    = (const int*)d_in[1];
    const int*   batch = (const int*)d_in[2];
    const float* w1  = (const float*)d_in[3];  const float* b1  = (const float*)d_in[4];
    const float* w2  = (const float*)d_in[5];  const float* b2  = (const float*)d_in[6];
    const float* w3  = (const float*)d_in[7];  const float* b3  = (const float*)d_in[8];
    const float* wg1 = (const float*)d_in[9];  const float* as1 = (const float*)d_in[10];
    const float* ad1 = (const float*)d_in[11]; const float* bg1 = (const float*)d_in[12];
    const float* wg2 = (const float*)d_in[13]; const float* as2 = (const float*)d_in[14];
    const float* ad2 = (const float*)d_in[15]; const float* bg2 = (const float*)d_in[16];
    const float* wc1 = (const float*)d_in[17]; const float* bc1 = (const float*)d_in[18];
    const float* wc2 = (const float*)d_in[19]; const float* bc2 = (const float*)d_in[20];

    const int* srcp = ei;            // edge_index[0]
    const int* dstp = ei + N_EDGES;  // edge_index[1]

    float *dinv, *aS, *aD, *selfc, *coef, *ppool;
    _Float16 *ah, *ch, *wh;
    int *degi, *bsum, *boff, *cursor, *rowptr, *csrsrc;
    hipGetSymbolAddress((void**)&ah,     HIP_SYMBOL(g_ah));
    hipGetSymbolAddress((void**)&ch,     HIP_SYMBOL(g_ch));
    hipGetSymbolAddress((void**)&wh,     HIP_SYMBOL(g_wh));
    hipGetSymbolAddress((void**)&dinv,   HIP_SYMBOL(g_dinv));
    hipGetSymbolAddress((void**)&degi,   HIP_SYMBOL(g_degi));
    hipGetSymbolAddress((void**)&bsum,   HIP_SYMBOL(g_bsum));
    hipGetSymbolAddress((void**)&boff,   HIP_SYMBOL(g_boff));
    hipGetSymbolAddress((void**)&cursor, HIP_SYMBOL(g_cursor));
    hipGetSymbolAddress((void**)&rowptr, HIP_SYMBOL(g_rowptr));
    hipGetSymbolAddress((void**)&csrsrc, HIP_SYMBOL(g_csrsrc));
    hipGetSymbolAddress((void**)&aS,     HIP_SYMBOL(g_aS));
    hipGetSymbolAddress((void**)&aD,     HIP_SYMBOL(g_aD));
    hipGetSymbolAddress((void**)&selfc,  HIP_SYMBOL(g_selfc));
    hipGetSymbolAddress((void**)&coef,   HIP_SYMBOL(g_coef));
    hipGetSymbolAddress((void**)&ppool,  HIP_SYMBOL(g_ppool));

    auto cdiv = [](int a, int b) { return (a + b - 1) / b; };
    int ggrid = 8 * cdiv(cdiv(N_NODES, 128), 8) * (H / 128);   // 2352
    int ngath = cdiv(N_NODES, 2);                              // 25000
    size_t HH = (size_t)H * H;

    // ---- weight transpose+cast, one launch, off the critical path ----
    split_wT4<<<cdiv(4*H*H,256),256,0,stream>>>(w2, w3, wg1, wg2, wh);

    // ---- CSR build (hierarchical scan) ----
    fill_i32<<<cdiv(N_NODES,256),256,0,stream>>>(degi, N_NODES, 0);
    count_deg<<<cdiv(N_EDGES,256),256,0,stream>>>(dstp, degi);
    scan1<<<NSB,256,0,stream>>>(degi, bsum);
    scan2<<<1,256,0,stream>>>(bsum, boff, rowptr);
    scan3<<<NSB,256,0,stream>>>(degi, boff, rowptr, cursor, dinv);
    bin_edges<<<cdiv(N_EDGES,256),256,0,stream>>>(srcp, dstp, cursor, csrsrc);

    // ---- GCN1: aggregate-first (3-dim) + matvec, single kernel ----
    gcn1_fused<<<ngath,192,0,stream>>>(rowptr, csrsrc, x, dinv, w1, b1, ah);

    // ---- GCN2 ----
    gemm_f16<<<ggrid,512,0,stream>>>(ah, wh + 0*HH, ch, N_NODES,
                                     (const float*)nullptr, (const float*)nullptr,
                                     (float*)nullptr, (float*)nullptr);
    gcn_gather<<<ngath,192,0,stream>>>(rowptr, csrsrc, ch, dinv, b2, ah);

    // ---- GCN3 ----
    gemm_f16<<<ggrid,512,0,stream>>>(ah, wh + 1*HH, ch, N_NODES,
                                     (const float*)nullptr, (const float*)nullptr,
                                     (float*)nullptr, (float*)nullptr);
    gcn_gather<<<ngath,192,0,stream>>>(rowptr, csrsrc, ch, dinv, b3, ah);

    // ---- GAT1 (alpha fused into GEMM; softmax precomputed; 1-pass gather) ----
    gemm_f16<<<ggrid,512,0,stream>>>(ah, wh + 2*HH, ch, N_NODES, as1, ad1, aS, aD);
    gat_stats<<<cdiv(N_NODES*NH,256),256,0,stream>>>(rowptr, csrsrc, aS, aD, selfc, coef);
    gat_gather<<<ngath,192,0,stream>>>(rowptr, csrsrc, ch, selfc, coef, bg1, ah, 1);

    // ---- GAT2 (no relu; fp16 out -> fp16 pooling) ----
    gemm_f16<<<ggrid,512,0,stream>>>(ah, wh + 3*HH, ch, N_NODES, as2, ad2, aS, aD);
    gat_stats<<<cdiv(N_NODES*NH,256),256,0,stream>>>(rowptr, csrsrc, aS, aD, selfc, coef);
    gat_gather<<<ngath,192,0,stream>>>(rowptr, csrsrc, ch, selfc, coef, bg2, ah, 0);

    // ---- pool (two-stage; stage-2 fused with mlp1+mlp2) ----
    pool_partial<<<NG*PCH,192,0,stream>>>(batch, ah, ppool);
    pool_mlp<<<NG,384,0,stream>>>(batch, ppool, wc1, bc1, wc2, bc2, (float*)d_out);
}

// Round 21
// 820.735 us; speedup vs baseline: 1.8178x; 1.8178x over previous
//
#include <hip/hip_runtime.h>
#include <math.h>

#define N_NODES 50000
#define N_EDGES 100000
#define H 768
#define NH 12
#define HD 64
#define NG 64
#define NC 10
#define H2 384
#define PCH 32   // pooling chunks per graph
#define NSB 196  // scan blocks = cdiv(N_NODES,256)

typedef _Float16 h8  __attribute__((ext_vector_type(8)));   // 8 fp16 (4 VGPR)
typedef _Float16 h4v __attribute__((ext_vector_type(4)));
typedef float    ffrag __attribute__((ext_vector_type(4))); // MFMA acc

// ---------------- static device scratch ----------------
__device__ _Float16 g_ah[(size_t)N_NODES * H];     // GEMM input acts fp16
__device__ _Float16 g_ch[(size_t)N_NODES * H];     // GEMM output / gather input fp16
__device__ _Float16 g_wh[4 * H * H];               // 4 weights^T fp16 [N][K]
__device__ float    g_dinv[N_NODES];
__device__ int      g_degi[N_NODES];
__device__ int      g_bsum[256];
__device__ int      g_boff[256];
__device__ int      g_cursor[N_NODES];
__device__ int      g_rowptr[N_NODES + 1];
__device__ int      g_csrsrc[N_EDGES];
__device__ float    g_aS[(size_t)N_NODES * NH];
__device__ float    g_aD[(size_t)N_NODES * NH];
__device__ float    g_selfc[(size_t)N_NODES * NH]; // GAT self-coefficient
__device__ float    g_coef[(size_t)N_EDGES * NH];  // GAT per-edge coefficient (4.8 MB)
__device__ float    g_ppool[(size_t)NG * PCH * H]; // pooling partials (6.3 MB)

__device__ inline int clampi(int v, int hi) { return (v < 0) ? 0 : (v >= hi ? hi - 1 : v); }

// async global->LDS, 16B per lane: lane i writes lds_base + i*16 (wave-uniform base)
__device__ inline void gload_lds16(const _Float16* g, _Float16* s) {
    __builtin_amdgcn_global_load_lds(
        (const __attribute__((address_space(1))) void*)g,
        (__attribute__((address_space(3))) void*)s, 16, 0, 0);
}

// ---------------- CSR build ----------------
__global__ void fill_i32(int* p, int n, int v) {
    int i = blockIdx.x * blockDim.x + threadIdx.x;
    if (i < n) p[i] = v;
}

__global__ void count_deg(const int* __restrict__ dst, int* __restrict__ degi) {
    int e = blockIdx.x * blockDim.x + threadIdx.x;
    if (e < N_EDGES) atomicAdd(&degi[clampi(dst[e], N_NODES)], 1);
}

// hierarchical scan (r13-verified)
__global__ __launch_bounds__(256) void scan1(const int* __restrict__ degi, int* __restrict__ bsum) {
    __shared__ int s[256];
    int b = blockIdx.x, t = threadIdx.x;
    int idx = b * 256 + t;
    s[t] = (idx < N_NODES) ? degi[idx] : 0;
    __syncthreads();
    for (int off = 128; off > 0; off >>= 1) {
        if (t < off) s[t] += s[t + off];
        __syncthreads();
    }
    if (t == 0) bsum[b] = s[0];
}

__global__ __launch_bounds__(256) void scan2(const int* __restrict__ bsum, int* __restrict__ boff,
                                             int* __restrict__ rowptr) {
    __shared__ int s[256];
    int t = threadIdx.x;
    int v = (t < NSB) ? bsum[t] : 0;
    s[t] = v;
    __syncthreads();
    for (int off = 1; off < 256; off <<= 1) {
        int x = (t >= off) ? s[t - off] : 0;
        __syncthreads();
        s[t] += x;
        __syncthreads();
    }
    if (t < NSB) boff[t] = s[t] - v;
    if (t == NSB - 1) rowptr[N_NODES] = s[t];
}

__global__ __launch_bounds__(256) void scan3(const int* __restrict__ degi, const int* __restrict__ boff,
                                             int* __restrict__ rowptr, int* __restrict__ cursor,
                                             float* __restrict__ dinv) {
    __shared__ int s[256];
    int b = blockIdx.x, t = threadIdx.x;
    int idx = b * 256 + t;
    int v = (idx < N_NODES) ? degi[idx] : 0;
    s[t] = v;
    __syncthreads();
    for (int off = 1; off < 256; off <<= 1) {
        int x = (t >= off) ? s[t - off] : 0;
        __syncthreads();
        s[t] += x;
        __syncthreads();
    }
    if (idx < N_NODES) {
        int excl = s[t] - v + boff[b];
        rowptr[idx] = excl;
        cursor[idx] = excl;
        dinv[idx] = rsqrtf((float)v + 1.0f);   // +1 = self-loop
    }
}

__global__ void bin_edges(const int* __restrict__ src, const int* __restrict__ dst,
                          int* __restrict__ cursor, int* __restrict__ csrsrc) {
    int e = blockIdx.x * blockDim.x + threadIdx.x;
    if (e >= N_EDGES) return;
    int d = clampi(dst[e], N_NODES);
    int pos = atomicAdd(&cursor[d], 1);
    if (pos >= 0 && pos < N_EDGES) csrsrc[pos] = clampi(src[e], N_NODES);
}

// all 4 big weights: w[K][N] fp32 -> transposed fp16 [N][K], one launch
__global__ void split_wT4(const float* __restrict__ w2, const float* __restrict__ w3,
                          const float* __restrict__ wg1, const float* __restrict__ wg2,
                          _Float16* __restrict__ out) {
    int idx = blockIdx.x * blockDim.x + threadIdx.x;
    if (idx >= 4 * H * H) return;
    int l = idx / (H * H), r = idx % (H * H);
    const float* w = (l == 0) ? w2 : (l == 1) ? w3 : (l == 2) ? wg1 : wg2;
    int n = r % H, k = r / H;
    out[(size_t)l * H * H + (size_t)n * H + k] = (_Float16)w[(size_t)k * H + n];
}

// ---- fused GCN1: aggregate x (3-dim!) then matvec w1 + bias + relu + fp16 ----
__global__ void gcn1_fused(const int* __restrict__ rowptr, const int* __restrict__ csrsrc,
                           const float* __restrict__ x, const float* __restrict__ dinv,
                           const float* __restrict__ w1, const float* __restrict__ b1,
                           _Float16* __restrict__ hi) {
    int d = blockIdx.x * 2 + (threadIdx.x / 96);
    int t = threadIdx.x % 96;
    if (d >= N_NODES) return;
    float dd = dinv[d];
    float c = dd * dd;
    float s0 = x[d*3] * c, s1 = x[d*3+1] * c, s2 = x[d*3+2] * c;
    int beg = rowptr[d], end = rowptr[d + 1];
    for (int i = beg; i < end; i++) {
        int s = csrsrc[i];
        float cc = dinv[s] * dd;
        s0 += x[s*3] * cc; s1 += x[s*3+1] * cc; s2 += x[s*3+2] * cc;
    }
    int j0 = t * 8;
    h8 o;
    #pragma unroll
    for (int k = 0; k < 8; k++) {
        int j = j0 + k;
        float v = s0 * w1[j] + s1 * w1[H + j] + s2 * w1[2*H + j] + b1[j];
        o[k] = (_Float16)fmaxf(v, 0.f);
    }
    ((h8*)(hi + (size_t)d * H))[t] = o;
}

// -- fp16 MFMA GEMM, 128x128 tile, 512 threads, BK=64 double-buffer ----------
// r19-proven config: 108 us/dispatch (session best). BK=64 halves the barrier
// count (drain model confirmed: 127->108). B-bypass falsified TWICE (r8: 382,
// r20: 275 us -- per-lane scattered B register loads put ~200cyc L2 latency
// inside the K-loop dependency chain; keep B in LDS via global_load_lds).
__global__ __launch_bounds__(512) void gemm_f16(const _Float16* __restrict__ a,
                                                const _Float16* __restrict__ bt,
                                                _Float16* __restrict__ C, int M,
                                                const float* __restrict__ asf,
                                                const float* __restrict__ adf,
                                                float* __restrict__ aS,
                                                float* __restrict__ aD) {
    __shared__ _Float16 sA[2][2][128 * 32], sB[2][2][128 * 32];
    int tid = threadIdx.x;
    int wave = tid >> 6, lane = tid & 63;
    int quad = lane >> 4, l16 = lane & 15;

    int id = blockIdx.x;
    int x = id & 7;
    int s = id >> 3;
    int strip = x + 8 * (s / 6);
    int colt = s % 6;
    if (strip >= (N_NODES + 127) / 128) return;
    int row0 = strip * 128, col0 = colt * 128;
    int wr = (wave >> 1) * 32, wc = (wave & 1) * 64;   // 4 row-waves x 2 col-waves

    // staging: 32 segs = {A,B} x khalf(2) x rowgroup(8); wave w stages 4w..4w+3
    int rr = lane >> 2;
    int kc = (((lane & 3) ^ ((lane >> 3) & 3)) << 3);   // XOR-swizzled source chunk
    const _Float16* gptr[4];
    int sel[4];      // 0 = A, 1 = B
    int soff[4];     // khalf*4096 + rowgroup*512
    #pragma unroll
    for (int k = 0; k < 4; k++) {
        int sg = wave * 4 + k;              // 0..31
        int isA = (sg < 16);
        int s2 = sg & 15;
        int khalf = s2 >> 3, rowgroup = s2 & 7;
        int r = (isA ? row0 : col0) + rowgroup * 16 + rr;
        if (isA && r >= M) r = M - 1;
        gptr[k] = (isA ? a : bt) + (size_t)r * H + khalf * 32 + kc;
        sel[k] = isA ? 0 : 1;
        soff[k] = khalf * 4096 + rowgroup * 512;
    }

    int fsw = (quad ^ ((l16 >> 1) & 3)) * 8;

    ffrag acc[2][4];
    #pragma unroll
    for (int i = 0; i < 2; i++)
        #pragma unroll
        for (int j = 0; j < 4; j++) { ffrag z = {0.f, 0.f, 0.f, 0.f}; acc[i][j] = z; }

    // prologue: stage k-tile 0 into buf 0
    #pragma unroll
    for (int k = 0; k < 4; k++)
        gload_lds16(gptr[k], (sel[k] ? &sB[0][0][0] : &sA[0][0][0]) + soff[k]);

    #pragma unroll 1
    for (int kt = 0; kt < H / 64; kt++) {
        int cur = kt & 1;
        __syncthreads();   // buf[cur] loads complete (compiler vmcnt drain)
        if (kt + 1 < H / 64) {
            int koff = (kt + 1) * 64;
            #pragma unroll
            for (int k = 0; k < 4; k++)
                gload_lds16(gptr[k] + koff,
                            (sel[k] ? &sB[cur ^ 1][0][0] : &sA[cur ^ 1][0][0]) + soff[k]);
        }

        #pragma unroll
        for (int kk = 0; kk < 2; kk++) {
            const _Float16* pA = sA[cur][kk];
            const _Float16* pB = sB[cur][kk];
            h8 fa[2], fb[4];
            #pragma unroll
            for (int i = 0; i < 2; i++)
                fa[i] = *reinterpret_cast<const h8*>(&pA[(wr + i * 16 + l16) * 32 + fsw]);
            #pragma unroll
            for (int j = 0; j < 4; j++)
                fb[j] = *reinterpret_cast<const h8*>(&pB[(wc + j * 16 + l16) * 32 + fsw]);
            #pragma unroll
            for (int i = 0; i < 2; i++)
                #pragma unroll
                for (int j = 0; j < 4; j++)
                    acc[i][j] = __builtin_amdgcn_mfma_f32_16x16x32_f16(fa[i], fb[j], acc[i][j], 0, 0, 0);
        }
    }

    // epilogue: C/D layout col=lane&15, row=quad*4+reg (m89-verified); fp16 store
    #pragma unroll
    for (int i = 0; i < 2; i++)
        #pragma unroll
        for (int r = 0; r < 4; r++) {
            int row = row0 + wr + i * 16 + quad * 4 + r;
            if (row >= M) continue;
            #pragma unroll
            for (int j = 0; j < 4; j++)
                C[(size_t)row * H + col0 + wc + j * 16 + l16] = (_Float16)acc[i][j][r];
        }

    // fused GAT alpha: this wave covers one full head (64 cols) for 32 rows
    if (asf) {
        int head = (col0 + wc) >> 6;
        float as_c[4], ad_c[4];
        #pragma unroll
        for (int j = 0; j < 4; j++) {
            int col = col0 + wc + j * 16 + l16;
            as_c[j] = asf[col];
            ad_c[j] = adf[col];
        }
        #pragma unroll
        for (int i = 0; i < 2; i++)
            #pragma unroll
            for (int r = 0; r < 4; r++) {
                float ps = 0.f, pd = 0.f;
                #pragma unroll
                for (int j = 0; j < 4; j++) {
                    ps += acc[i][j][r] * as_c[j];
                    pd += acc[i][j][r] * ad_c[j];
                }
                ps += __shfl_xor(ps, 1);  pd += __shfl_xor(pd, 1);
                ps += __shfl_xor(ps, 2);  pd += __shfl_xor(pd, 2);
                ps += __shfl_xor(ps, 4);  pd += __shfl_xor(pd, 4);
                ps += __shfl_xor(ps, 8);  pd += __shfl_xor(pd, 8);
                int row = row0 + wr + i * 16 + quad * 4 + r;
                if (l16 == 0 && row < M) {
                    aS[row * NH + head] = ps;
                    aD[row * NH + head] = pd;
                }
            }
    }
}

// ------- fused GCN gather: 2 nodes/block, 16B h8 loads (r14-verified) --------
__global__ void gcn_gather(const int* __restrict__ rowptr, const int* __restrict__ csrsrc,
                           const _Float16* __restrict__ h, const float* __restrict__ dinv,
                           const float* __restrict__ bias, _Float16* __restrict__ hi) {
    int d = blockIdx.x * 2 + (threadIdx.x / 96);
    int t = threadIdx.x % 96;   // h8-chunk index (96 x 8 halves = 768)
    if (d >= N_NODES) return;
    float dd = dinv[d];
    float c = dd * dd;
    h8 v = ((const h8*)(h + (size_t)d * H))[t];
    float acc[8];
    #pragma unroll
    for (int k = 0; k < 8; k++) acc[k] = (float)v[k] * c;
    int beg = rowptr[d], end = rowptr[d + 1];
    for (int i = beg; i < end; i++) {
        int s = csrsrc[i];
        float cc = dinv[s] * dd;
        h8 u = ((const h8*)(h + (size_t)s * H))[t];
        #pragma unroll
        for (int k = 0; k < 8; k++) acc[k] += (float)u[k] * cc;
    }
    float4 b0 = ((const float4*)bias)[2 * t];
    float4 b1 = ((const float4*)bias)[2 * t + 1];
    h8 o;
    o[0] = (_Float16)fmaxf(acc[0] + b0.x, 0.f);
    o[1] = (_Float16)fmaxf(acc[1] + b0.y, 0.f);
    o[2] = (_Float16)fmaxf(acc[2] + b0.z, 0.f);
    o[3] = (_Float16)fmaxf(acc[3] + b0.w, 0.f);
    o[4] = (_Float16)fmaxf(acc[4] + b1.x, 0.f);
    o[5] = (_Float16)fmaxf(acc[5] + b1.y, 0.f);
    o[6] = (_Float16)fmaxf(acc[6] + b1.z, 0.f);
    o[7] = (_Float16)fmaxf(acc[7] + b1.w, 0.f);
    ((h8*)(hi + (size_t)d * H))[t] = o;
}

__device__ inline float lrelu(float v) { return (v > 0.f) ? v : 0.2f * v; }

// ---- GAT softmax stats: one thread per (node, head) (r18-verified) ----
__global__ void gat_stats(const int* __restrict__ rowptr, const int* __restrict__ csrsrc,
                          const float* __restrict__ aS, const float* __restrict__ aD,
                          float* __restrict__ selfc, float* __restrict__ coef) {
    int idx = blockIdx.x * blockDim.x + threadIdx.x;
    if (idx >= N_NODES * NH) return;
    int d = idx / NH, hh = idx % NH;
    int beg = rowptr[d], end = rowptr[d + 1];
    float adv = aD[idx];
    float eself = lrelu(aS[idx] + adv);
    float m = eself;
    for (int i = beg; i < end; i++)
        m = fmaxf(m, lrelu(aS[csrsrc[i] * NH + hh] + adv));
    float ssum = __expf(eself - m);
    for (int i = beg; i < end; i++)
        ssum += __expf(lrelu(aS[csrsrc[i] * NH + hh] + adv) - m);
    float inv = 1.0f / ssum;
    selfc[idx] = __expf(eself - m) * inv;
    for (int i = beg; i < end; i++)
        coef[(size_t)i * NH + hh] = __expf(lrelu(aS[csrsrc[i] * NH + hh] + adv) - m) * inv;
}

// fused GAT aggregation: single pass, precomputed coefficients; fp16 out.
__global__ void gat_gather(const int* __restrict__ rowptr, const int* __restrict__ csrsrc,
                           const _Float16* __restrict__ h, const float* __restrict__ selfc,
                           const float* __restrict__ coef, const float* __restrict__ bias,
                           _Float16* __restrict__ hi, int relu) {
    int d = blockIdx.x * 2 + (threadIdx.x / 96);
    int t = threadIdx.x % 96;
    if (d >= N_NODES) return;
    int hh = t >> 3;
    int beg = rowptr[d], end = rowptr[d + 1];
    float cself = selfc[d * NH + hh];
    h8 v = ((const h8*)(h + (size_t)d * H))[t];
    float acc[8];
    #pragma unroll
    for (int k = 0; k < 8; k++) acc[k] = (float)v[k] * cself;
    for (int i = beg; i < end; i++) {
        int s = csrsrc[i];
        float c = coef[(size_t)i * NH + hh];
        h8 u = ((const h8*)(h + (size_t)s * H))[t];
        #pragma unroll
        for (int k = 0; k < 8; k++) acc[k] += (float)u[k] * c;
    }
    float4 b0 = ((const float4*)bias)[2 * t];
    float4 b1 = ((const float4*)bias)[2 * t + 1];
    acc[0] += b0.x; acc[1] += b0.y; acc[2] += b0.z; acc[3] += b0.w;
    acc[4] += b1.x; acc[5] += b1.y; acc[6] += b1.z; acc[7] += b1.w;
    if (relu) {
        #pragma unroll
        for (int k = 0; k < 8; k++) acc[k] = fmaxf(acc[k], 0.f);
    }
    h8 o;
    #pragma unroll
    for (int k = 0; k < 8; k++) o[k] = (_Float16)acc[k];
    ((h8*)(hi + (size_t)d * H))[t] = o;
}

// ---------------- pooling (batch is sorted), two-stage + fused mlp1+mlp2 ------
__device__ inline int lower_bound_i(const int* b, int n, int key) {
    int lo = 0, hi = n;
    while (lo < hi) { int mid = (lo + hi) >> 1; if (b[mid] < key) lo = mid + 1; else hi = mid; }
    return lo;
}

__global__ void pool_partial(const int* __restrict__ batch, const _Float16* __restrict__ h,
                             float* __restrict__ ppool) {
    int g = blockIdx.x / PCH, c = blockIdx.x % PCH;
    int t = threadIdx.x;   // 0..191, h4v chunks
    int lo = lower_bound_i(batch, N_NODES, g);
    int hi = lower_bound_i(batch, N_NODES, g + 1);
    int len = hi - lo;
    int chunk = (len + PCH - 1) / PCH;
    int s = lo + c * chunk;
    int e = s + chunk; if (e > hi) e = hi;
    float4 a = {0, 0, 0, 0};
    for (int n = s; n < e; n++) {
        h4v v = ((const h4v*)(h + (size_t)n * H))[t];
        a.x += (float)v[0]; a.y += (float)v[1]; a.z += (float)v[2]; a.w += (float)v[3];
    }
    ((float4*)(ppool + (size_t)blockIdx.x * H))[t] = a;
}

// reduce partials -> mean row -> z = relu(row@wc1+bc1) -> logits = z@wc2+bc2
__global__ __launch_bounds__(384) void pool_mlp(const int* __restrict__ batch,
                                                const float* __restrict__ ppool,
                                                const float* __restrict__ wc1,
                                                const float* __restrict__ bc1,
                                                const float* __restrict__ wc2,
                                                const float* __restrict__ bc2,
                                                float* __restrict__ out) {
    __shared__ float row[H];
    __shared__ float z[H2];
    int g = blockIdx.x, t = threadIdx.x;   // 384 threads
    int lo = lower_bound_i(batch, N_NODES, g);
    int hi = lower_bound_i(batch, N_NODES, g + 1);
    float inv = 1.0f / fmaxf((float)(hi - lo), 1.0f);
    for (int c0 = t; c0 < H; c0 += 384) {
        float a = 0.f;
        for (int c = 0; c < PCH; c++) a += ppool[(size_t)(g * PCH + c) * H + c0];
        row[c0] = a * inv;
    }
    __syncthreads();
    float acc = bc1[t];
    for (int k = 0; k < H; k++) acc += row[k] * wc1[(size_t)k * H2 + t];
    z[t] = fmaxf(acc, 0.f);
    __syncthreads();
    if (t < NC) {
        float l = bc2[t];
        for (int k = 0; k < H2; k++) l += z[k] * wc2[(size_t)k * NC + t];
        out[g * NC + t] = l;
    }
}

// ---------------- launch ----------------
extern "C" void kernel_launch(void* const* d_in, const int* in_sizes, int n_in,
                              void* d_out, int out_size, void* d_ws, size_t ws_size,
                              hipStream_t stream) {
    (void)d_ws; (void)ws_size;
    const float* x     = (const float*)d_in[0];
    const int*   ei    = (const int*)d_in[1];
    const int*   batch = (const int*)d_in[2];
    const float* w1  = (const float*)d_in[3];  const float* b1  = (const float*)d_in[4];
    const float* w2  = (const float*)d_in[5];  const float* b2  = (const float*)d_in[6];
    const float* w3  = (const float*)d_in[7];  const float* b3  = (const float*)d_in[8];
    const float* wg1 = (const float*)d_in[9];  const float* as1 = (const float*)d_in[10];
    const float* ad1 = (const float*)d_in[11]; const float* bg1 = (const float*)d_in[12];
    const float* wg2 = (const float*)d_in[13]; const float* as2 = (const float*)d_in[14];
    const float* ad2 = (const float*)d_in[15]; const float* bg2 = (const float*)d_in[16];
    const float* wc1 = (const float*)d_in[17]; const float* bc1 = (const float*)d_in[18];
    const float* wc2 = (const float*)d_in[19]; const float* bc2 = (const float*)d_in[20];

    const int* srcp = ei;            // edge_index[0]
    const int* dstp = ei + N_EDGES;  // edge_index[1]

    float *dinv, *aS, *aD, *selfc, *coef, *ppool;
    _Float16 *ah, *ch, *wh;
    int *degi, *bsum, *boff, *cursor, *rowptr, *csrsrc;
    hipGetSymbolAddress((void**)&ah,     HIP_SYMBOL(g_ah));
    hipGetSymbolAddress((void**)&ch,     HIP_SYMBOL(g_ch));
    hipGetSymbolAddress((void**)&wh,     HIP_SYMBOL(g_wh));
    hipGetSymbolAddress((void**)&dinv,   HIP_SYMBOL(g_dinv));
    hipGetSymbolAddress((void**)&degi,   HIP_SYMBOL(g_degi));
    hipGetSymbolAddress((void**)&bsum,   HIP_SYMBOL(g_bsum));
    hipGetSymbolAddress((void**)&boff,   HIP_SYMBOL(g_boff));
    hipGetSymbolAddress((void**)&cursor, HIP_SYMBOL(g_cursor));
    hipGetSymbolAddress((void**)&rowptr, HIP_SYMBOL(g_rowptr));
    hipGetSymbolAddress((void**)&csrsrc, HIP_SYMBOL(g_csrsrc));
    hipGetSymbolAddress((void**)&aS,     HIP_SYMBOL(g_aS));
    hipGetSymbolAddress((void**)&aD,     HIP_SYMBOL(g_aD));
    hipGetSymbolAddress((void**)&selfc,  HIP_SYMBOL(g_selfc));
    hipGetSymbolAddress((void**)&coef,   HIP_SYMBOL(g_coef));
    hipGetSymbolAddress((void**)&ppool,  HIP_SYMBOL(g_ppool));

    auto cdiv = [](int a, int b) { return (a + b - 1) / b; };
    int ggrid = 8 * cdiv(cdiv(N_NODES, 128), 8) * (H / 128);   // 2352
    int ngath = cdiv(N_NODES, 2);                              // 25000
    size_t HH = (size_t)H * H;

    // ---- weight transpose+cast, one launch, off the critical path ----
    split_wT4<<<cdiv(4*H*H,256),256,0,stream>>>(w2, w3, wg1, wg2, wh);

    // ---- CSR build (hierarchical scan) ----
    fill_i32<<<cdiv(N_NODES,256),256,0,stream>>>(degi, N_NODES, 0);
    count_deg<<<cdiv(N_EDGES,256),256,0,stream>>>(dstp, degi);
    scan1<<<NSB,256,0,stream>>>(degi, bsum);
    scan2<<<1,256,0,stream>>>(bsum, boff, rowptr);
    scan3<<<NSB,256,0,stream>>>(degi, boff, rowptr, cursor, dinv);
    bin_edges<<<cdiv(N_EDGES,256),256,0,stream>>>(srcp, dstp, cursor, csrsrc);

    // ---- GCN1: aggregate-first (3-dim) + matvec, single kernel ----
    gcn1_fused<<<ngath,192,0,stream>>>(rowptr, csrsrc, x, dinv, w1, b1, ah);

    // ---- GCN2 ----
    gemm_f16<<<ggrid,512,0,stream>>>(ah, wh + 0*HH, ch, N_NODES,
                                     (const float*)nullptr, (const float*)nullptr,
                                     (float*)nullptr, (float*)nullptr);
    gcn_gather<<<ngath,192,0,stream>>>(rowptr, csrsrc, ch, dinv, b2, ah);

    // ---- GCN3 ----
    gemm_f16<<<ggrid,512,0,stream>>>(ah, wh + 1*HH, ch, N_NODES,
                                     (const float*)nullptr, (const float*)nullptr,
                                     (float*)nullptr, (float*)nullptr);
    gcn_gather<<<ngath,192,0,stream>>>(rowptr, csrsrc, ch, dinv, b3, ah);

    // ---- GAT1 (alpha fused into GEMM; softmax precomputed; 1-pass gather) ----
    gemm_f16<<<ggrid,512,0,stream>>>(ah, wh + 2*HH, ch, N_NODES, as1, ad1, aS, aD);
    gat_stats<<<cdiv(N_NODES*NH,256),256,0,stream>>>(rowptr, csrsrc, aS, aD, selfc, coef);
    gat_gather<<<ngath,192,0,stream>>>(rowptr, csrsrc, ch, selfc, coef, bg1, ah, 1);

    // ---- GAT2 (no relu; fp16 out -> fp16 pooling) ----
    gemm_f16<<<ggrid,512,0,stream>>>(ah, wh + 3*HH, ch, N_NODES, as2, ad2, aS, aD);
    gat_stats<<<cdiv(N_NODES*NH,256),256,0,stream>>>(rowptr, csrsrc, aS, aD, selfc, coef);
    gat_gather<<<ngath,192,0,stream>>>(rowptr, csrsrc, ch, selfc, coef, bg2, ah, 0);

    // ---- pool (two-stage; stage-2 fused with mlp1+mlp2) ----
    pool_partial<<<NG*PCH,192,0,stream>>>(batch, ah, ppool);
    pool_mlp<<<NG,384,0,stream>>>(batch, ppool, wc1, bc1, wc2, bc2, (float*)d_out);
}